// Round 6
// baseline (95.876 us; speedup 1.0000x reference)
//
#include <hip/hip_runtime.h>

// ExodusNet: weighted = W[1,32] @ x[B,32,T]  ->  LIF scan over T -> spikes [B,1,T]
// B = 32768, F = 32 (C*H*W), T = 100. All float32.
//
// Memory-bound: x = 419 MB read (no reuse), out = 13 MB write.
//   Phase 1: per-block, compute weighted[32 b][100 t] with float4 loads over T
//            (coalesced; every x element read exactly once), stage in LDS.
//   Phase 2: 1 thread per batch element runs the sequential 100-step LIF scan
//            in LDS (XOR-swizzled float4 rows -> bank-conflict-free).
//   Phase 3: coalesced float4 stores of the spike outputs.
//
// R2/R3: NB=32, grid=1024 (4 blocks/CU), W read via scalar broadcast. 83.6 us.
// R4: wave-independent (no barriers) — neutral (86.1). Structure is not the
//     limiter; effective BW stuck at ~5.17 TB/s across all variants.
// R5/R6: nontemporal (nt) loads for the 419 MB zero-reuse x stream, nt stores
//     for spikes — tests whether L2/L3 tag allocation throttles the stream.
//     R6 fixes R5's compile error: the builtins need clang ext_vector_type,
//     not HIP_vector_type.

#define NB     32      // batch elements per block
#define BLOCK  256     // threads per block
#define TT     100     // time steps
#define FF     32      // features
#define T4     (TT/4)  // 25 float4 groups per row
#define ROWPAD 128     // dwords per LDS row (32 float4 slots: t4 ^ (bl&7) fits)

typedef float vf4 __attribute__((ext_vector_type(4)));

__global__ __launch_bounds__(BLOCK) void exodus_lif_kernel(
        const float* __restrict__ x,
        const float* __restrict__ Wg,
        float* __restrict__ out)
{
    __shared__ __align__(16) float wbuf[NB * ROWPAD];  // 16 KB

    const int  tid = threadIdx.x;
    const long b0  = (long)blockIdx.x * NB;

    // ---- Phase 1: weighted[bl][t] = sum_f W[f] * x[b0+bl, f, t] ----
    const int NITEM = NB * T4;  // 800
    for (int item = tid; item < NITEM; item += BLOCK) {
        const int bl = item / T4;
        const int t4 = item % T4;
        const vf4* xp =
            reinterpret_cast<const vf4*>(x + (b0 + bl) * (long)(FF * TT) + t4 * 4);
        vf4 a0 = (vf4)0.f;
        vf4 a1 = (vf4)0.f;
#pragma unroll
        for (int f = 0; f < 16; ++f) {
            const vf4   xv = __builtin_nontemporal_load(&xp[f * T4]);
            const float w  = Wg[f];   // uniform address -> scalar load broadcast
            a0 += w * xv;
        }
#pragma unroll
        for (int f = 16; f < 32; ++f) {
            const vf4   xv = __builtin_nontemporal_load(&xp[f * T4]);
            const float w  = Wg[f];
            a1 += w * xv;
        }
        a0 += a1;
        const int t4s = t4 ^ (bl & 7);  // bank swizzle
        *reinterpret_cast<vf4*>(&wbuf[bl * ROWPAD + t4s * 4]) = a0;
    }
    __syncthreads();

    // ---- Phase 2: sequential LIF scan, one thread per batch element ----
    if (tid < NB) {
        const float A  = 0.90483741803595952f;  // exp(-1/10)
        const float OM = 0.09516258196404048f;  // 1 - A
        const int   bl = tid;
        float v = 0.f;
#pragma unroll
        for (int t4 = 0; t4 < T4; ++t4) {
            const int t4s = t4 ^ (bl & 7);
            vf4 w = *reinterpret_cast<vf4*>(&wbuf[bl * ROWPAD + t4s * 4]);
#pragma unroll
            for (int k = 0; k < 4; ++k) {
                v = A * v + OM * w[k];
                const float s = (v >= 1.0f) ? 1.0f : 0.0f;
                v -= s;
                w[k] = s;
            }
            *reinterpret_cast<vf4*>(&wbuf[bl * ROWPAD + t4s * 4]) = w;
        }
    }
    __syncthreads();

    // ---- Phase 3: coalesced spike writeback (nt stores, no reuse) ----
    for (int item = tid; item < NITEM; item += BLOCK) {
        const int bl  = item / T4;
        const int t4  = item % T4;
        const int t4s = t4 ^ (bl & 7);
        const vf4 s = *reinterpret_cast<const vf4*>(&wbuf[bl * ROWPAD + t4s * 4]);
        __builtin_nontemporal_store(s,
            reinterpret_cast<vf4*>(out + (b0 + bl) * (long)TT + t4 * 4));
    }
}

extern "C" void kernel_launch(void* const* d_in, const int* in_sizes, int n_in,
                              void* d_out, int out_size, void* d_ws, size_t ws_size,
                              hipStream_t stream) {
    const float* x  = (const float*)d_in[0];   // [32768, 2, 4, 4, 100] = [B, 32, 100]
    const float* Wg = (const float*)d_in[1];   // [1, 32]
    float* out      = (float*)d_out;           // [32768, 1, 100]

    const int B    = in_sizes[0] / (FF * TT);  // 32768
    const int grid = B / NB;                   // 1024

    exodus_lif_kernel<<<grid, BLOCK, 0, stream>>>(x, Wg, out);
}

// Round 7
// 84.141 us; speedup vs baseline: 1.1395x; 1.1395x over previous
//
#include <hip/hip_runtime.h>

// ExodusNet: weighted = W[1,32] @ x[B,32,T]  ->  LIF scan over T -> spikes [B,1,T]
// B = 32768, F = 32 (C*H*W), T = 100. All float32.
//
// Memory-bound: x = 419 MB read (no reuse), out = 13 MB write.
//   Phase 1: per-block, compute weighted[32 b][100 t] with float4 loads over T
//            (coalesced; every x element read exactly once), stage in LDS.
//   Phase 2: 1 thread per batch element runs the sequential 100-step LIF scan
//            in LDS (XOR-swizzled float4 rows -> bank-conflict-free).
//   Phase 3: coalesced float4 stores of the spike outputs.
//
// R3: NB=32, grid=1024, scalar-broadcast W. 83.6 us = 5.17 TB/s (82% of copy BW).
// R4: wave-independent/barrier-free — neutral. R6: nontemporal — HURT (95.9,
//     nt defeats boundary-line merging of the unaligned 400 B rows). Reverted.
// R7: max memory-level parallelism probe — all 32 float4 loads issued into a
//     fully-unrolled register array BEFORE any FMA (128 dest VGPRs), testing
//     whether per-wave outstanding-load depth (not wave count) was the limiter.

#define NB     32      // batch elements per block
#define BLOCK  256     // threads per block
#define TT     100     // time steps
#define FF     32      // features
#define T4     (TT/4)  // 25 float4 groups per row
#define ROWPAD 128     // dwords per LDS row (32 float4 slots: t4 ^ (bl&7) fits)

typedef float vf4 __attribute__((ext_vector_type(4)));

__global__ __launch_bounds__(BLOCK) void exodus_lif_kernel(
        const float* __restrict__ x,
        const float* __restrict__ Wg,
        float* __restrict__ out)
{
    __shared__ __align__(16) float wbuf[NB * ROWPAD];  // 16 KB

    const int  tid = threadIdx.x;
    const long b0  = (long)blockIdx.x * NB;

    // ---- Phase 1: weighted[bl][t] = sum_f W[f] * x[b0+bl, f, t] ----
    const int NITEM = NB * T4;  // 800
    for (int item = tid; item < NITEM; item += BLOCK) {
        const int bl = item / T4;
        const int t4 = item % T4;
        const vf4* xp =
            reinterpret_cast<const vf4*>(x + (b0 + bl) * (long)(FF * TT) + t4 * 4);

        // Issue all 32 loads before consuming any -> max outstanding vmcnt.
        vf4 xv[FF];
#pragma unroll
        for (int f = 0; f < FF; ++f) xv[f] = xp[f * T4];

        vf4 a0 = (vf4)0.f, a1 = (vf4)0.f, a2 = (vf4)0.f, a3 = (vf4)0.f;
#pragma unroll
        for (int f = 0; f < FF; f += 4) {
            a0 += Wg[f + 0] * xv[f + 0];
            a1 += Wg[f + 1] * xv[f + 1];
            a2 += Wg[f + 2] * xv[f + 2];
            a3 += Wg[f + 3] * xv[f + 3];
        }
        a0 += a1; a2 += a3; a0 += a2;

        const int t4s = t4 ^ (bl & 7);  // bank swizzle
        *reinterpret_cast<vf4*>(&wbuf[bl * ROWPAD + t4s * 4]) = a0;
    }
    __syncthreads();

    // ---- Phase 2: sequential LIF scan, one thread per batch element ----
    if (tid < NB) {
        const float A  = 0.90483741803595952f;  // exp(-1/10)
        const float OM = 0.09516258196404048f;  // 1 - A
        const int   bl = tid;
        float v = 0.f;
#pragma unroll
        for (int t4 = 0; t4 < T4; ++t4) {
            const int t4s = t4 ^ (bl & 7);
            vf4 w = *reinterpret_cast<vf4*>(&wbuf[bl * ROWPAD + t4s * 4]);
#pragma unroll
            for (int k = 0; k < 4; ++k) {
                v = A * v + OM * w[k];
                const float s = (v >= 1.0f) ? 1.0f : 0.0f;
                v -= s;
                w[k] = s;
            }
            *reinterpret_cast<vf4*>(&wbuf[bl * ROWPAD + t4s * 4]) = w;
        }
    }
    __syncthreads();

    // ---- Phase 3: coalesced spike writeback ----
    for (int item = tid; item < NITEM; item += BLOCK) {
        const int bl  = item / T4;
        const int t4  = item % T4;
        const int t4s = t4 ^ (bl & 7);
        const vf4 s = *reinterpret_cast<const vf4*>(&wbuf[bl * ROWPAD + t4s * 4]);
        *reinterpret_cast<vf4*>(out + (b0 + bl) * (long)TT + t4 * 4) = s;
    }
}

extern "C" void kernel_launch(void* const* d_in, const int* in_sizes, int n_in,
                              void* d_out, int out_size, void* d_ws, size_t ws_size,
                              hipStream_t stream) {
    const float* x  = (const float*)d_in[0];   // [32768, 2, 4, 4, 100] = [B, 32, 100]
    const float* Wg = (const float*)d_in[1];   // [1, 32]
    float* out      = (float*)d_out;           // [32768, 1, 100]

    const int B    = in_sizes[0] / (FF * TT);  // 32768
    const int grid = B / NB;                   // 1024

    exodus_lif_kernel<<<grid, BLOCK, 0, stream>>>(x, Wg, out);
}